// Round 4
// baseline (191.755 us; speedup 1.0000x reference)
//
#include <hip/hip_runtime.h>
#include <hip/hip_bf16.h>

typedef __attribute__((ext_vector_type(8))) short bf16x8;
typedef __attribute__((ext_vector_type(4))) float f32x4;
typedef __attribute__((ext_vector_type(4))) float fvec4;
typedef __attribute__((ext_vector_type(8))) unsigned short u16x8;

// B=4, T=256, U=64 -> M = 65536 rows; K(J)=512; N(V)=1024

__device__ __forceinline__ unsigned short f2bf(float f) {
  unsigned int u = __builtin_bit_cast(unsigned int, f);
  u += 0x7FFFu + ((u >> 16) & 1u);   // round-to-nearest-even
  return (unsigned short)(u >> 16);
}

__device__ __forceinline__ float fast_tanh(float x) {
  float cx = fminf(fmaxf(x, -9.0f), 9.0f);
  float e2 = __expf(cx + cx);
  return (e2 - 1.0f) * __builtin_amdgcn_rcpf(e2 + 1.0f);
}

// ---- fused prep: enc-proj (blocks 0..127), pred-proj (128..159), W_out^T (160..287)

__device__ __forceinline__ void proj_body(
    const float* __restrict__ x, const float* __restrict__ W,
    const float* __restrict__ bias, float* __restrict__ out,
    int blk, uint8_t* sh) {
  float (*xt)[9] = (float (*)[9])sh;   // [256][9] f32 = 9216 B
  const int tid = threadIdx.x;
  const int row0 = blk << 3;
  #pragma unroll
  for (int i = 0; i < 8; ++i)
    xt[tid][i] = x[(size_t)(row0 + i) * 256 + tid];
  __syncthreads();
  float acc0[8] = {0.f,0.f,0.f,0.f,0.f,0.f,0.f,0.f};
  float acc1[8] = {0.f,0.f,0.f,0.f,0.f,0.f,0.f,0.f};
  #pragma unroll 4
  for (int k = 0; k < 256; ++k) {
    float w0 = W[(size_t)k * 512 + tid];
    float w1 = W[(size_t)k * 512 + tid + 256];
    #pragma unroll
    for (int r = 0; r < 8; ++r) {
      float xv = xt[k][r];
      acc0[r] = fmaf(xv, w0, acc0[r]);
      acc1[r] = fmaf(xv, w1, acc1[r]);
    }
  }
  float b0 = bias[tid], b1 = bias[tid + 256];
  #pragma unroll
  for (int r = 0; r < 8; ++r) {
    out[(size_t)(row0 + r) * 512 + tid]       = acc0[r] + b0;
    out[(size_t)(row0 + r) * 512 + tid + 256] = acc1[r] + b1;
  }
}

__device__ __forceinline__ void transpose_body(
    const float* __restrict__ W, unsigned short* __restrict__ Wt,
    int blk, uint8_t* sh) {
  unsigned short (*tile)[65] = (unsigned short (*)[65])sh;  // [64][65] = 8320 B
  const int k0 = (blk & 7) << 6;
  const int n0 = (blk >> 3) << 6;
  const int tid = threadIdx.x;
  #pragma unroll
  for (int i = 0; i < 16; ++i) {
    int idx = tid + (i << 8);
    int r = idx >> 6, c = idx & 63;
    tile[r][c] = f2bf(W[(size_t)(k0 + r) * 1024 + n0 + c]);
  }
  __syncthreads();
  #pragma unroll
  for (int i = 0; i < 16; ++i) {
    int idx = tid + (i << 8);
    int r = idx >> 6, c = idx & 63;
    Wt[(size_t)(n0 + r) * 512 + k0 + c] = tile[c][r];
  }
}

__global__ __launch_bounds__(256) void prep_kernel(
    const float* __restrict__ enc, const float* __restrict__ We,
    const float* __restrict__ be, float* __restrict__ encp,
    const float* __restrict__ pred, const float* __restrict__ Wd,
    const float* __restrict__ bd, float* __restrict__ predp,
    const float* __restrict__ Wo, unsigned short* __restrict__ Wt) {
  __shared__ uint8_t sh[9216];
  const int b = blockIdx.x;
  if (b < 128)       proj_body(enc, We, be, encp, b, sh);
  else if (b < 160)  proj_body(pred, Wd, bd, predp, b - 128, sh);
  else               transpose_body(Wo, Wt, b - 160, sh);
}

// ---- fused joint+gemm: BM=64 (one encp row), BN=1024 (full vocab), K=512.
// Block mt: A[r][k] = bf16(tanh(encp[mt][k] + predp[(mt>>8)*64 + r][k])) computed
// once into XOR-swizzled LDS (64 KiB, resident all K). B-frags read directly
// from L2 (Wt is 1 MiB, resident; zero intra-block reuse -> LDS staging useless).
// K-loop is BARRIER-FREE: 8 waves x (64M x 128N), reg-double-buffered B frags.
// MFMA operands swapped: lane holds C[m=lane&15-dim][n=reg-dim] -> dwordx4 stores.
__global__ __launch_bounds__(512, 2) void fused_gemm(
    const float* __restrict__ encp, const float* __restrict__ predp,
    const unsigned short* __restrict__ Bt, const float* __restrict__ bout,
    float* __restrict__ out) {
  __shared__ uint8_t Alds[64 * 1024];   // [64 rows][512 bf16], 16B-chunk XOR swizzle
  const int tid = threadIdx.x;
  const int lane = tid & 63, wid = tid >> 6;
  const int fr = lane & 15, fg = lane >> 4;
  const int mt = blockIdx.x;          // 0..1023
  const int m0 = mt << 6;
  const int nw = wid << 7;            // wave's 128-col N slice

  // B lane base: row (nw+fr), k-chunk fg (16B); frag nf at +nf*16 rows; kt at +32 k
  const unsigned short* Bl = Bt + (size_t)(nw + fr) * 512 + (fg << 3);

  bf16x8 bA[8], bB[8];
  #pragma unroll
  for (int nf = 0; nf < 8; ++nf)      // issue tile-0 B loads before tanh phase
    bA[nf] = *(const bf16x8*)(Bl + (nf << 13));

  // ---- phase 0: A tile -> swizzled LDS.  f(row,chunk) = row*1024 + ((chunk^(row&7))<<4)
  {
    const int r = tid >> 3, cb = tid & 7;
    const float* erow = encp + ((size_t)mt << 9);
    const float* prow = predp + ((size_t)(((mt >> 8) << 6) + r) << 9);
    uint8_t* rowbase = Alds + (r << 10);
    #pragma unroll
    for (int c8 = 0; c8 < 8; ++c8) {
      int chunk = cb + (c8 << 3);
      int k8 = chunk << 3;
      fvec4 e0 = *(const fvec4*)(erow + k8);
      fvec4 e1 = *(const fvec4*)(erow + k8 + 4);
      fvec4 p0 = *(const fvec4*)(prow + k8);
      fvec4 p1 = *(const fvec4*)(prow + k8 + 4);
      u16x8 o;
      #pragma unroll
      for (int i = 0; i < 4; ++i) o[i]     = f2bf(fast_tanh(e0[i] + p0[i]));
      #pragma unroll
      for (int i = 0; i < 4; ++i) o[i + 4] = f2bf(fast_tanh(e1[i] + p1[i]));
      *(u16x8*)(rowbase + ((chunk ^ (r & 7)) << 4)) = o;
    }
  }
  __syncthreads();

  f32x4 acc[4][8];
  f32x4 zero4 = {0.f, 0.f, 0.f, 0.f};
  #pragma unroll
  for (int i = 0; i < 4; ++i)
    #pragma unroll
    for (int j = 0; j < 8; ++j) acc[i][j] = zero4;

  // one K-step: prefetch B(kt+1) into nxt, read A frags from LDS, 32 MFMA on cur
  auto step = [&](int kt, bf16x8 (&cur)[8], bf16x8 (&nxt)[8]) {
    const int ktn = kt < 15 ? kt + 1 : 15;   // last iter: harmless dup reload
    #pragma unroll
    for (int nf = 0; nf < 8; ++nf)
      nxt[nf] = *(const bf16x8*)(Bl + (nf << 13) + (ktn << 5));
    bf16x8 af[4];
    #pragma unroll
    for (int mf = 0; mf < 4; ++mf) {
      const int aoff = ((((kt << 2) | fg) ^ (fr & 7)) << 4);  // swizzled chunk
      af[mf] = *(const bf16x8*)(Alds + ((((mf << 4) + fr)) << 10) + aoff);
    }
    #pragma unroll
    for (int mf = 0; mf < 4; ++mf)
      #pragma unroll
      for (int nf = 0; nf < 8; ++nf)
        acc[mf][nf] = __builtin_amdgcn_mfma_f32_16x16x32_bf16(cur[nf], af[mf],
                                                              acc[mf][nf], 0, 0, 0);
  };

  #pragma unroll
  for (int kt = 0; kt < 16; kt += 2) {   // static ping-pong (rule #20)
    step(kt,     bA, bB);
    step(kt + 1, bB, bA);
  }

  // epilogue: frag (mf,nf): C[m0+mf*16+fr][nw+nf*16+fg*4 .. +3]
  #pragma unroll
  for (int nf = 0; nf < 8; ++nf) {
    const int gn = nw + (nf << 4) + (fg << 2);
    const fvec4 bv = *(const fvec4*)&bout[gn];
    #pragma unroll
    for (int mf = 0; mf < 4; ++mf) {
      const int gm = m0 + (mf << 4) + fr;
      fvec4 o = acc[mf][nf] + bv;
      *(fvec4*)&out[(size_t)gm * 1024 + gn] = o;
    }
  }
}

extern "C" void kernel_launch(void* const* d_in, const int* in_sizes, int n_in,
                              void* d_out, int out_size, void* d_ws, size_t ws_size,
                              hipStream_t stream) {
  const float* enc   = (const float*)d_in[0];
  const float* pred  = (const float*)d_in[1];
  const float* W_enc = (const float*)d_in[2];
  const float* b_enc = (const float*)d_in[3];
  const float* W_dec = (const float*)d_in[4];
  const float* b_dec = (const float*)d_in[5];
  const float* W_out = (const float*)d_in[6];
  const float* b_out = (const float*)d_in[7];
  float* out = (float*)d_out;

  uint8_t* ws = (uint8_t*)d_ws;
  float* encp  = (float*)ws;                           // [1024][512] f32, 2 MiB
  float* predp = (float*)(ws + 2097152);               // [256][512]  f32, 0.5 MiB
  unsigned short* wt = (unsigned short*)(ws + 2621440);// [1024][512] bf16, 1 MiB

  prep_kernel<<<288, 256, 0, stream>>>(enc, W_enc, b_enc, encp,
                                       pred, W_dec, b_dec, predp,
                                       W_out, wt);
  fused_gemm<<<1024, 512, 0, stream>>>(encp, predp, wt, b_out, out);
}

// Round 5
// 187.495 us; speedup vs baseline: 1.0227x; 1.0227x over previous
//
#include <hip/hip_runtime.h>
#include <hip/hip_bf16.h>

typedef __attribute__((ext_vector_type(8))) short bf16x8;
typedef __attribute__((ext_vector_type(4))) float f32x4;
typedef __attribute__((ext_vector_type(4))) float fvec4;
typedef __attribute__((ext_vector_type(8))) unsigned short u16x8;

// B=4, T=256, U=64 -> M = 65536 rows; K(J)=512; N(V)=1024

__device__ __forceinline__ unsigned short f2bf(float f) {
  unsigned int u = __builtin_bit_cast(unsigned int, f);
  u += 0x7FFFu + ((u >> 16) & 1u);   // round-to-nearest-even
  return (unsigned short)(u >> 16);
}

__device__ __forceinline__ float fast_tanh(float x) {
  float cx = fminf(fmaxf(x, -9.0f), 9.0f);
  float e2 = __expf(cx + cx);
  return (e2 - 1.0f) * __builtin_amdgcn_rcpf(e2 + 1.0f);
}

// ---- fused prep: enc-proj (blocks 0..127), pred-proj (128..159), W_out^T (160..287)

__device__ __forceinline__ void proj_body(
    const float* __restrict__ x, const float* __restrict__ W,
    const float* __restrict__ bias, float* __restrict__ out,
    int blk, uint8_t* sh) {
  float (*xt)[9] = (float (*)[9])sh;   // [256][9] f32 = 9216 B
  const int tid = threadIdx.x;
  const int row0 = blk << 3;
  #pragma unroll
  for (int i = 0; i < 8; ++i)
    xt[tid][i] = x[(size_t)(row0 + i) * 256 + tid];
  __syncthreads();
  float acc0[8] = {0.f,0.f,0.f,0.f,0.f,0.f,0.f,0.f};
  float acc1[8] = {0.f,0.f,0.f,0.f,0.f,0.f,0.f,0.f};
  #pragma unroll 4
  for (int k = 0; k < 256; ++k) {
    float w0 = W[(size_t)k * 512 + tid];
    float w1 = W[(size_t)k * 512 + tid + 256];
    #pragma unroll
    for (int r = 0; r < 8; ++r) {
      float xv = xt[k][r];
      acc0[r] = fmaf(xv, w0, acc0[r]);
      acc1[r] = fmaf(xv, w1, acc1[r]);
    }
  }
  float b0 = bias[tid], b1 = bias[tid + 256];
  #pragma unroll
  for (int r = 0; r < 8; ++r) {
    out[(size_t)(row0 + r) * 512 + tid]       = acc0[r] + b0;
    out[(size_t)(row0 + r) * 512 + tid + 256] = acc1[r] + b1;
  }
}

__device__ __forceinline__ void transpose_body(
    const float* __restrict__ W, unsigned short* __restrict__ Wt,
    int blk, uint8_t* sh) {
  unsigned short (*tile)[65] = (unsigned short (*)[65])sh;  // [64][65] = 8320 B
  const int k0 = (blk & 7) << 6;
  const int n0 = (blk >> 3) << 6;
  const int tid = threadIdx.x;
  #pragma unroll
  for (int i = 0; i < 16; ++i) {
    int idx = tid + (i << 8);
    int r = idx >> 6, c = idx & 63;
    tile[r][c] = f2bf(W[(size_t)(k0 + r) * 1024 + n0 + c]);
  }
  __syncthreads();
  #pragma unroll
  for (int i = 0; i < 16; ++i) {
    int idx = tid + (i << 8);
    int r = idx >> 6, c = idx & 63;
    Wt[(size_t)(n0 + r) * 512 + k0 + c] = tile[c][r];
  }
}

__global__ __launch_bounds__(256) void prep_kernel(
    const float* __restrict__ enc, const float* __restrict__ We,
    const float* __restrict__ be, float* __restrict__ encp,
    const float* __restrict__ pred, const float* __restrict__ Wd,
    const float* __restrict__ bd, float* __restrict__ predp,
    const float* __restrict__ Wo, unsigned short* __restrict__ Wt) {
  __shared__ uint8_t sh[9216];
  const int b = blockIdx.x;
  if (b < 128)       proj_body(enc, We, be, encp, b, sh);
  else if (b < 160)  proj_body(pred, Wd, bd, predp, b - 128, sh);
  else               transpose_body(Wo, Wt, b - 160, sh);
}

// ---- fused joint+gemm: BM=64 (one encp row), BN=512, K=512.
// A = bf16(tanh(encp+predp)) computed ONCE into XOR-swizzled LDS (64 KiB,
// resident for all K -> barrier-free K-loop). B-frags direct from L2
// (Wt 1 MiB resident), register double-buffered.
// OCCUPANCY IS THE POINT: per-wave 64x64 output -> acc 64 AGPR, B-dbuf 32 +
// A-frags 16 VGPR; __launch_bounds__(512,4) caps at 128 regs/wave so
// 2 blocks/CU (16 waves) fit -- r4's 64x128/wave needed ~244 -> 1 block/CU.
// MFMA operands swapped: lane holds C[m=lane&15-dim][n=reg-dim] -> dwordx4 stores.
__global__ __launch_bounds__(512, 4) void fused_gemm(
    const float* __restrict__ encp, const float* __restrict__ predp,
    const unsigned short* __restrict__ Bt, const float* __restrict__ bout,
    float* __restrict__ out) {
  __shared__ uint8_t Alds[64 * 1024];   // [64 rows][512 bf16], 16B-chunk XOR swizzle
  const int tid = threadIdx.x;
  const int lane = tid & 63, wid = tid >> 6;
  const int fr = lane & 15, fg = lane >> 4;
  const int b = blockIdx.x;
  const int wg = ((b & 7) << 8) + (b >> 3);   // XCD swizzle, 2048 % 8 == 0 (bijective)
  const int mt = wg >> 1;                      // 0..1023 (nt inner: pair shares A)
  const int m0 = mt << 6;
  const int nw = ((wg & 1) << 9) + (wid << 6); // wave's 64-col N slice

  // B lane base: row (nw+fr), k-chunk fg (16B); frag nf at +16 rows; kt at +64 B imm
  const unsigned short* Bl = Bt + (size_t)(nw + fr) * 512 + (fg << 3);

  bf16x8 bA[4], bB[4];
  #pragma unroll
  for (int nf = 0; nf < 4; ++nf)      // issue tile-0 B loads before tanh phase
    bA[nf] = *(const bf16x8*)(Bl + (nf << 13));

  // ---- phase 0: A tile -> swizzled LDS.  f(row,chunk) = row*1024 + ((chunk^(row&7))<<4)
  {
    const int r = tid >> 3, cb = tid & 7;
    const float* erow = encp + ((size_t)mt << 9);
    const float* prow = predp + ((size_t)(((mt >> 8) << 6) + r) << 9);
    uint8_t* rowbase = Alds + (r << 10);
    #pragma unroll
    for (int c8 = 0; c8 < 8; ++c8) {
      int chunk = cb + (c8 << 3);
      int k8 = chunk << 3;
      fvec4 e0 = *(const fvec4*)(erow + k8);
      fvec4 e1 = *(const fvec4*)(erow + k8 + 4);
      fvec4 p0 = *(const fvec4*)(prow + k8);
      fvec4 p1 = *(const fvec4*)(prow + k8 + 4);
      u16x8 o;
      #pragma unroll
      for (int i = 0; i < 4; ++i) o[i]     = f2bf(fast_tanh(e0[i] + p0[i]));
      #pragma unroll
      for (int i = 0; i < 4; ++i) o[i + 4] = f2bf(fast_tanh(e1[i] + p1[i]));
      *(u16x8*)(rowbase + ((chunk ^ (r & 7)) << 4)) = o;
    }
  }
  __syncthreads();

  f32x4 acc[4][4];
  f32x4 zero4 = {0.f, 0.f, 0.f, 0.f};
  #pragma unroll
  for (int i = 0; i < 4; ++i)
    #pragma unroll
    for (int j = 0; j < 4; ++j) acc[i][j] = zero4;

  // A read addr: chunk = ((kt<<2)|fg) ^ (fr&7) = ((kt^qh)<<2) | (fg^(fr&3))
  const int qh = (fr >> 2) & 1;
  int arow[4];
  #pragma unroll
  for (int mf = 0; mf < 4; ++mf)
    arow[mf] = ((((mf << 4) + fr)) << 10) + ((fg ^ (fr & 3)) << 4);

  // one K-step: prefetch B(kt+1) into nxt, read A frags from LDS, 16 MFMA on cur
  auto step = [&](int kt, bf16x8 (&cur)[4], bf16x8 (&nxt)[4]) {
    const int ktn = kt < 15 ? kt + 1 : 15;   // last iter: harmless dup reload
    #pragma unroll
    for (int nf = 0; nf < 4; ++nf)
      nxt[nf] = *(const bf16x8*)(Bl + (nf << 13) + (ktn << 5));
    const int ko = (kt ^ qh) << 6;
    bf16x8 af[4];
    #pragma unroll
    for (int mf = 0; mf < 4; ++mf)
      af[mf] = *(const bf16x8*)(Alds + arow[mf] + ko);
    #pragma unroll
    for (int mf = 0; mf < 4; ++mf)
      #pragma unroll
      for (int nf = 0; nf < 4; ++nf)
        acc[mf][nf] = __builtin_amdgcn_mfma_f32_16x16x32_bf16(cur[nf], af[mf],
                                                              acc[mf][nf], 0, 0, 0);
  };

  #pragma unroll
  for (int kt = 0; kt < 16; kt += 2) {   // static ping-pong (rule #20)
    step(kt,     bA, bB);
    step(kt + 1, bB, bA);
  }

  // epilogue: frag (mf,nf): C[m0+mf*16+fr][nw+nf*16+fg*4 .. +3]
  #pragma unroll
  for (int nf = 0; nf < 4; ++nf) {
    const int gn = nw + (nf << 4) + (fg << 2);
    const fvec4 bv = *(const fvec4*)&bout[gn];
    #pragma unroll
    for (int mf = 0; mf < 4; ++mf) {
      const int gm = m0 + (mf << 4) + fr;
      fvec4 o = acc[mf][nf] + bv;
      *(fvec4*)&out[(size_t)gm * 1024 + gn] = o;
    }
  }
}

extern "C" void kernel_launch(void* const* d_in, const int* in_sizes, int n_in,
                              void* d_out, int out_size, void* d_ws, size_t ws_size,
                              hipStream_t stream) {
  const float* enc   = (const float*)d_in[0];
  const float* pred  = (const float*)d_in[1];
  const float* W_enc = (const float*)d_in[2];
  const float* b_enc = (const float*)d_in[3];
  const float* W_dec = (const float*)d_in[4];
  const float* b_dec = (const float*)d_in[5];
  const float* W_out = (const float*)d_in[6];
  const float* b_out = (const float*)d_in[7];
  float* out = (float*)d_out;

  uint8_t* ws = (uint8_t*)d_ws;
  float* encp  = (float*)ws;                           // [1024][512] f32, 2 MiB
  float* predp = (float*)(ws + 2097152);               // [256][512]  f32, 0.5 MiB
  unsigned short* wt = (unsigned short*)(ws + 2621440);// [1024][512] bf16, 1 MiB

  prep_kernel<<<288, 256, 0, stream>>>(enc, W_enc, b_enc, encp,
                                       pred, W_dec, b_dec, predp,
                                       W_out, wt);
  fused_gemm<<<2048, 512, 0, stream>>>(encp, predp, wt, b_out, out);
}

// Round 6
// 181.208 us; speedup vs baseline: 1.0582x; 1.0347x over previous
//
#include <hip/hip_runtime.h>
#include <hip/hip_bf16.h>

typedef __attribute__((ext_vector_type(8))) short bf16x8;
typedef __attribute__((ext_vector_type(4))) float f32x4;
typedef __attribute__((ext_vector_type(4))) float fvec4;
typedef __attribute__((ext_vector_type(8))) unsigned short u16x8;

// B=4, T=256, U=64 -> M = 65536 rows; K(J)=512; N(V)=1024

__device__ __forceinline__ unsigned short f2bf(float f) {
  unsigned int u = __builtin_bit_cast(unsigned int, f);
  u += 0x7FFFu + ((u >> 16) & 1u);   // round-to-nearest-even
  return (unsigned short)(u >> 16);
}

__device__ __forceinline__ float fast_tanh(float x) {
  float cx = fminf(fmaxf(x, -9.0f), 9.0f);
  float e2 = __expf(cx + cx);
  return (e2 - 1.0f) * __builtin_amdgcn_rcpf(e2 + 1.0f);
}

// ---- fused prep: enc-proj (blocks 0..127), pred-proj (128..159), W_out^T (160..287)

__device__ __forceinline__ void proj_body(
    const float* __restrict__ x, const float* __restrict__ W,
    const float* __restrict__ bias, float* __restrict__ out,
    int blk, uint8_t* sh) {
  float (*xt)[9] = (float (*)[9])sh;   // [256][9] f32 = 9216 B
  const int tid = threadIdx.x;
  const int row0 = blk << 3;
  #pragma unroll
  for (int i = 0; i < 8; ++i)
    xt[tid][i] = x[(size_t)(row0 + i) * 256 + tid];
  __syncthreads();
  float acc0[8] = {0.f,0.f,0.f,0.f,0.f,0.f,0.f,0.f};
  float acc1[8] = {0.f,0.f,0.f,0.f,0.f,0.f,0.f,0.f};
  #pragma unroll 4
  for (int k = 0; k < 256; ++k) {
    float w0 = W[(size_t)k * 512 + tid];
    float w1 = W[(size_t)k * 512 + tid + 256];
    #pragma unroll
    for (int r = 0; r < 8; ++r) {
      float xv = xt[k][r];
      acc0[r] = fmaf(xv, w0, acc0[r]);
      acc1[r] = fmaf(xv, w1, acc1[r]);
    }
  }
  float b0 = bias[tid], b1 = bias[tid + 256];
  #pragma unroll
  for (int r = 0; r < 8; ++r) {
    out[(size_t)(row0 + r) * 512 + tid]       = acc0[r] + b0;
    out[(size_t)(row0 + r) * 512 + tid + 256] = acc1[r] + b1;
  }
}

__device__ __forceinline__ void transpose_body(
    const float* __restrict__ W, unsigned short* __restrict__ Wt,
    int blk, uint8_t* sh) {
  unsigned short (*tile)[65] = (unsigned short (*)[65])sh;  // [64][65] = 8320 B
  const int k0 = (blk & 7) << 6;
  const int n0 = (blk >> 3) << 6;
  const int tid = threadIdx.x;
  #pragma unroll
  for (int i = 0; i < 16; ++i) {
    int idx = tid + (i << 8);
    int r = idx >> 6, c = idx & 63;
    tile[r][c] = f2bf(W[(size_t)(k0 + r) * 1024 + n0 + c]);
  }
  __syncthreads();
  #pragma unroll
  for (int i = 0; i < 16; ++i) {
    int idx = tid + (i << 8);
    int r = idx >> 6, c = idx & 63;
    Wt[(size_t)(n0 + r) * 512 + k0 + c] = tile[c][r];
  }
}

__global__ __launch_bounds__(256) void prep_kernel(
    const float* __restrict__ enc, const float* __restrict__ We,
    const float* __restrict__ be, float* __restrict__ encp,
    const float* __restrict__ pred, const float* __restrict__ Wd,
    const float* __restrict__ bd, float* __restrict__ predp,
    const float* __restrict__ Wo, unsigned short* __restrict__ Wt) {
  __shared__ uint8_t sh[9216];
  const int b = blockIdx.x;
  if (b < 128)       proj_body(enc, We, be, encp, b, sh);
  else if (b < 160)  proj_body(pred, Wd, bd, predp, b - 128, sh);
  else               transpose_body(Wo, Wt, b - 160, sh);
}

// ---- fused joint+gemm: BM=64 (one encp row), BN=512, K=512.
// A = bf16(tanh(encp+predp)) computed ONCE into XOR-swizzled LDS (resident for
// all K -> barrier-free K-loop). B-frags direct from L2, reg double-buffered.
// 8 waves x (64M x 64N), acc 64 AGPR, launch_bounds(512,4) -> 2 blocks/CU.
// EPILOGUE THROUGH LDS (round 6 change): r5 stored 16x64B scattered segments
// per instr -> effective write BW ~1.6 TB/s bound the kernel. Now: 4 rounds
// (one per mf quadrant); waves deposit bias-added acc into a [16][516] f32
// padded LDS tile, barrier, stream back as CONTIGUOUS 1KiB-per-instr stores.
__global__ __launch_bounds__(512, 4) void fused_gemm(
    const float* __restrict__ encp, const float* __restrict__ predp,
    const unsigned short* __restrict__ Bt, const float* __restrict__ bout,
    float* __restrict__ out) {
  __shared__ uint8_t Alds[65536];   // A: [64 rows][512 bf16] swizzled; epi: [16][516] f32
  const int tid = threadIdx.x;
  const int lane = tid & 63, wid = tid >> 6;
  const int fr = lane & 15, fg = lane >> 4;
  const int b = blockIdx.x;
  const int wg = ((b & 7) << 8) + (b >> 3);   // XCD swizzle, 2048 % 8 == 0 (bijective)
  const int mt = wg >> 1;                      // 0..1023 (nt inner: pair shares A)
  const int m0 = mt << 6;
  const int cb0 = (wg & 1) << 9;               // block's 512-col half of vocab
  const int nw = cb0 + (wid << 6);             // wave's 64-col N slice

  // B lane base: row (nw+fr), k-chunk fg (16B); frag nf at +16 rows; kt at +64 B
  const unsigned short* Bl = Bt + (size_t)(nw + fr) * 512 + (fg << 3);

  bf16x8 bA[4], bB[4];
  #pragma unroll
  for (int nf = 0; nf < 4; ++nf)      // issue tile-0 B loads before tanh phase
    bA[nf] = *(const bf16x8*)(Bl + (nf << 13));

  // ---- phase 0: A tile -> swizzled LDS.  f(row,chunk) = row*1024 + ((chunk^(row&7))<<4)
  {
    const int r = tid >> 3, cb = tid & 7;
    const float* erow = encp + ((size_t)mt << 9);
    const float* prow = predp + ((size_t)(((mt >> 8) << 6) + r) << 9);
    uint8_t* rowbase = Alds + (r << 10);
    #pragma unroll
    for (int c8 = 0; c8 < 8; ++c8) {
      int chunk = cb + (c8 << 3);
      int k8 = chunk << 3;
      fvec4 e0 = *(const fvec4*)(erow + k8);
      fvec4 e1 = *(const fvec4*)(erow + k8 + 4);
      fvec4 p0 = *(const fvec4*)(prow + k8);
      fvec4 p1 = *(const fvec4*)(prow + k8 + 4);
      u16x8 o;
      #pragma unroll
      for (int i = 0; i < 4; ++i) o[i]     = f2bf(fast_tanh(e0[i] + p0[i]));
      #pragma unroll
      for (int i = 0; i < 4; ++i) o[i + 4] = f2bf(fast_tanh(e1[i] + p1[i]));
      *(u16x8*)(rowbase + ((chunk ^ (r & 7)) << 4)) = o;
    }
  }
  __syncthreads();

  f32x4 acc[4][4];
  f32x4 zero4 = {0.f, 0.f, 0.f, 0.f};
  #pragma unroll
  for (int i = 0; i < 4; ++i)
    #pragma unroll
    for (int j = 0; j < 4; ++j) acc[i][j] = zero4;

  // A read addr: chunk = ((kt<<2)|fg) ^ (fr&7) = ((kt^qh)<<2) | (fg^(fr&3))
  const int qh = (fr >> 2) & 1;
  int arow[4];
  #pragma unroll
  for (int mf = 0; mf < 4; ++mf)
    arow[mf] = ((((mf << 4) + fr)) << 10) + ((fg ^ (fr & 3)) << 4);

  // one K-step: prefetch B(kt+1) into nxt, read A frags from LDS, 16 MFMA on cur
  auto step = [&](int kt, bf16x8 (&cur)[4], bf16x8 (&nxt)[4]) {
    const int ktn = kt < 15 ? kt + 1 : 15;   // last iter: harmless dup reload
    #pragma unroll
    for (int nf = 0; nf < 4; ++nf)
      nxt[nf] = *(const bf16x8*)(Bl + (nf << 13) + (ktn << 5));
    const int ko = (kt ^ qh) << 6;
    bf16x8 af[4];
    #pragma unroll
    for (int mf = 0; mf < 4; ++mf)
      af[mf] = *(const bf16x8*)(Alds + arow[mf] + ko);
    #pragma unroll
    for (int mf = 0; mf < 4; ++mf)
      #pragma unroll
      for (int nf = 0; nf < 4; ++nf)
        acc[mf][nf] = __builtin_amdgcn_mfma_f32_16x16x32_bf16(cur[nf], af[mf],
                                                              acc[mf][nf], 0, 0, 0);
  };

  #pragma unroll
  for (int kt = 0; kt < 16; kt += 2) {   // static ping-pong (rule #20)
    step(kt,     bA, bB);
    step(kt + 1, bB, bA);
  }

  // ---- epilogue through LDS: 4 rounds (one per mf quadrant = 16 M-rows).
  // deposit: lane (fr,fg) of wave wid writes rows fr, in-block cols
  // wid*64+nf*16+fg*4 into epi[16][516] (pad 4 -> bank-floor, no conflict).
  // drain: instr idx = wid*4+j -> row idx>>1, seg idx&1; 64 lanes read
  // epi[row][seg*256 + lane*4 ..] = 1 KiB contiguous -> 1 store instr/KiB.
  float (*epi)[516] = (float (*)[516])Alds;
  const int colw = (wid << 6) + (fg << 2);
  fvec4 bvv[4];
  #pragma unroll
  for (int nf = 0; nf < 4; ++nf)
    bvv[nf] = *(const fvec4*)&bout[cb0 + colw + (nf << 4)];

  #pragma unroll
  for (int mf = 0; mf < 4; ++mf) {
    __syncthreads();   // prev round's LDS reads (or K-loop A reads) done
    #pragma unroll
    for (int nf = 0; nf < 4; ++nf) {
      fvec4 o = acc[mf][nf] + bvv[nf];
      *(fvec4*)&epi[fr][colw + (nf << 4)] = o;
    }
    __syncthreads();
    #pragma unroll
    for (int j = 0; j < 4; ++j) {
      const int idx = (wid << 2) + j;
      const int row = idx >> 1, seg = idx & 1;
      fvec4 v = *(const fvec4*)&epi[row][(seg << 8) + (lane << 2)];
      *(fvec4*)&out[(size_t)(m0 + (mf << 4) + row) * 1024 + cb0 +
                    (seg << 8) + (lane << 2)] = v;
    }
  }
}

extern "C" void kernel_launch(void* const* d_in, const int* in_sizes, int n_in,
                              void* d_out, int out_size, void* d_ws, size_t ws_size,
                              hipStream_t stream) {
  const float* enc   = (const float*)d_in[0];
  const float* pred  = (const float*)d_in[1];
  const float* W_enc = (const float*)d_in[2];
  const float* b_enc = (const float*)d_in[3];
  const float* W_dec = (const float*)d_in[4];
  const float* b_dec = (const float*)d_in[5];
  const float* W_out = (const float*)d_in[6];
  const float* b_out = (const float*)d_in[7];
  float* out = (float*)d_out;

  uint8_t* ws = (uint8_t*)d_ws;
  float* encp  = (float*)ws;                           // [1024][512] f32, 2 MiB
  float* predp = (float*)(ws + 2097152);               // [256][512]  f32, 0.5 MiB
  unsigned short* wt = (unsigned short*)(ws + 2621440);// [1024][512] bf16, 1 MiB

  prep_kernel<<<288, 256, 0, stream>>>(enc, W_enc, b_enc, encp,
                                       pred, W_dec, b_dec, predp,
                                       W_out, wt);
  fused_gemm<<<2048, 512, 0, stream>>>(encp, predp, wt, b_out, out);
}

// Round 7
// 172.468 us; speedup vs baseline: 1.1118x; 1.0507x over previous
//
#include <hip/hip_runtime.h>
#include <hip/hip_bf16.h>

typedef __attribute__((ext_vector_type(8))) short bf16x8;
typedef __attribute__((ext_vector_type(4))) float f32x4;
typedef __attribute__((ext_vector_type(4))) float fvec4;
typedef __attribute__((ext_vector_type(8))) unsigned short u16x8;
typedef __attribute__((ext_vector_type(4))) unsigned short u16x4;

// B=4, T=256, U=64 -> M = 65536 rows; K(J)=512; N(V)=1024

__device__ __forceinline__ unsigned short f2bf(float f) {
  unsigned int u = __builtin_bit_cast(unsigned int, f);
  u += 0x7FFFu + ((u >> 16) & 1u);   // round-to-nearest-even
  return (unsigned short)(u >> 16);
}

__device__ __forceinline__ float fast_tanh(float x) {
  float cx = fminf(fmaxf(x, -9.0f), 9.0f);
  float e2 = __expf(cx + cx);
  return (e2 - 1.0f) * __builtin_amdgcn_rcpf(e2 + 1.0f);
}

// ---- fused prep: enc-proj (blocks 0..127), pred-proj (128..159), W_out^T (160..287)

__device__ __forceinline__ void proj_body(
    const float* __restrict__ x, const float* __restrict__ W,
    const float* __restrict__ bias, float* __restrict__ out,
    int blk, uint8_t* sh) {
  float (*xt)[9] = (float (*)[9])sh;   // [256][9] f32 = 9216 B
  const int tid = threadIdx.x;
  const int row0 = blk << 3;
  #pragma unroll
  for (int i = 0; i < 8; ++i)
    xt[tid][i] = x[(size_t)(row0 + i) * 256 + tid];
  __syncthreads();
  float acc0[8] = {0.f,0.f,0.f,0.f,0.f,0.f,0.f,0.f};
  float acc1[8] = {0.f,0.f,0.f,0.f,0.f,0.f,0.f,0.f};
  #pragma unroll 4
  for (int k = 0; k < 256; ++k) {
    float w0 = W[(size_t)k * 512 + tid];
    float w1 = W[(size_t)k * 512 + tid + 256];
    #pragma unroll
    for (int r = 0; r < 8; ++r) {
      float xv = xt[k][r];
      acc0[r] = fmaf(xv, w0, acc0[r]);
      acc1[r] = fmaf(xv, w1, acc1[r]);
    }
  }
  float b0 = bias[tid], b1 = bias[tid + 256];
  #pragma unroll
  for (int r = 0; r < 8; ++r) {
    out[(size_t)(row0 + r) * 512 + tid]       = acc0[r] + b0;
    out[(size_t)(row0 + r) * 512 + tid + 256] = acc1[r] + b1;
  }
}

// W_out [512 k][1024 n] f32 -> Bt2 K-MAJOR bf16: index =
//   (n>>9)*262144 + (k>>5)*16384 + (n&511)*32 + (k&31)
// so each (half, kt) slice is a CONTIGUOUS 32 KiB block (512 n-rows x 32 k).
__device__ __forceinline__ void transpose_body(
    const float* __restrict__ W, unsigned short* __restrict__ Bt2,
    int blk, uint8_t* sh) {
  unsigned short (*tile)[65] = (unsigned short (*)[65])sh;  // [64 k][65 n]
  const int k0 = (blk & 7) << 6;
  const int n0 = (blk >> 3) << 6;
  const int tid = threadIdx.x;
  #pragma unroll
  for (int i = 0; i < 16; ++i) {
    int idx = tid + (i << 8);
    int r = idx >> 6, c = idx & 63;        // r = k-off, c = n-off (coalesced read)
    tile[r][c] = f2bf(W[(size_t)(k0 + r) * 1024 + n0 + c]);
  }
  __syncthreads();
  #pragma unroll
  for (int i = 0; i < 16; ++i) {
    int idx = tid + (i << 8);
    int r = idx >> 6, c = idx & 63;        // r = n-off, c = k-off
    int ng = n0 + r, kg = k0 + c;
    size_t dst = ((size_t)(ng >> 9) << 18) + ((size_t)(kg >> 5) << 14)
               + ((ng & 511) << 5) + (kg & 31);
    Bt2[dst] = tile[c][r];
  }
}

__global__ __launch_bounds__(256) void prep_kernel(
    const float* __restrict__ enc, const float* __restrict__ We,
    const float* __restrict__ be, float* __restrict__ encp,
    const float* __restrict__ pred, const float* __restrict__ Wd,
    const float* __restrict__ bd, float* __restrict__ predp,
    const float* __restrict__ Wo, unsigned short* __restrict__ Bt2) {
  __shared__ uint8_t sh[9216];
  const int b = blockIdx.x;
  if (b < 128)       proj_body(enc, We, be, encp, b, sh);
  else if (b < 160)  proj_body(pred, Wd, bd, predp, b - 128, sh);
  else               transpose_body(Wo, Bt2, b - 160, sh);
}

// ---- fused joint+gemm: BM=64, BN=512, BK=32, 16 K-steps, 8 waves (64x64 each).
// B: 3 rotating LDS slots (32 KiB each), staged depth-2 via global_load_lds from
//   the K-major Bt2 (both sides perfectly linear, 1 KiB per wave-instr).
// A: [64][32] bf16 dbuf (2x4 KiB) recomputed per K-step from tanh(encp+predp)
//   (2x chip-wide tanh redundancy ~ 6 us; frees LDS vs A-resident).
// Ordering per step keeps B(kt+2) in flight across the barrier: ep loads are
//   issued BEFORE stageB, so the tanh's implicit vm-wait drains only ep+B(kt+1).
// lgkmcnt(0) before each raw s_barrier publishes ds_writes; each wave's own
//   vm-drain publishes its global_load_lds quarter before the barrier -> no race.
__global__ __launch_bounds__(512, 2) void fused_gemm(
    const float* __restrict__ encp, const float* __restrict__ predp,
    const unsigned short* __restrict__ Bt2, const float* __restrict__ bout,
    float* __restrict__ out) {
  __shared__ uint8_t Bl[3][32768];
  __shared__ uint8_t Al[2][4096];
  const int tid = threadIdx.x;
  const int lane = tid & 63, wid = tid >> 6;
  const int fr = lane & 15, fg = lane >> 4;
  const int b = blockIdx.x;
  const int wg = ((b & 7) << 8) + (b >> 3);   // XCD swizzle, 2048 % 8 == 0
  const int mt = wg >> 1, half = wg & 1;      // half inner: pair shares encp row
  const int m0 = mt << 6;
  const int cb0 = half << 9;

  const unsigned short* Bbase = Bt2 + ((size_t)half << 18);

  auto stageB = [&](int kt) {
    const unsigned short* src = Bbase + (kt << 14);
    uint8_t* dst = &Bl[kt % 3][0];
    #pragma unroll
    for (int i = 0; i < 4; ++i) {
      int c = (i << 9) + tid;
      __builtin_amdgcn_global_load_lds(
          (const __attribute__((address_space(1))) void*)(src + (c << 3)),
          (__attribute__((address_space(3))) void*)(dst + (c << 4)), 16, 0, 0);
    }
  };

  // A compute: thread -> row = tid>>3 (0..63), c8 = tid&7 (4 k each)
  const int arow = tid >> 3, ac8 = tid & 7;
  const float* erow = encp + ((size_t)mt << 9) + (ac8 << 2);
  const float* prow = predp + ((size_t)(((mt >> 8) << 6) + arow) << 9) + (ac8 << 2);
  uint8_t* awr0 = &Al[0][(arow << 6) + (ac8 << 3)];
  uint8_t* awr1 = &Al[1][(arow << 6) + (ac8 << 3)];

  // prologue: B(0), B(1) in flight; A(0) computed; full drain once.
  stageB(0);
  stageB(1);
  {
    fvec4 e = *(const fvec4*)(erow);
    fvec4 p = *(const fvec4*)(prow);
    u16x4 o;
    #pragma unroll
    for (int i = 0; i < 4; ++i) o[i] = f2bf(fast_tanh(e[i] + p[i]));
    *(u16x4*)awr0 = o;
  }
  const int colw = (wid << 6) + (fg << 2);
  fvec4 bvv[4];
  #pragma unroll
  for (int nf = 0; nf < 4; ++nf)
    bvv[nf] = *(const fvec4*)&bout[cb0 + colw + (nf << 4)];
  __syncthreads();

  f32x4 acc[4][4];
  f32x4 zero4 = {0.f, 0.f, 0.f, 0.f};
  #pragma unroll
  for (int i = 0; i < 4; ++i)
    #pragma unroll
    for (int j = 0; j < 4; ++j) acc[i][j] = zero4;

  const int aoffb = (fr << 6) + (fg << 4);            // A frag base (row fr)
  const int boffb = (wid << 12) + (fr << 6) + (fg << 4);  // B frag base

  #pragma unroll
  for (int kt = 0; kt < 16; ++kt) {
    // 1) issue next-step ep loads FIRST (keeps B(kt+2) younger in vmcnt queue)
    fvec4 e, p;
    if (kt < 15) {
      e = *(const fvec4*)(erow + ((kt + 1) << 5));
      p = *(const fvec4*)(prow + ((kt + 1) << 5));
    }
    __builtin_amdgcn_sched_barrier(0);
    // 2) stage B(kt+2)
    if (kt < 14) stageB(kt + 2);
    // 3) fragments for this step
    const uint8_t* sB = &Bl[kt % 3][0];
    const uint8_t* sA = &Al[kt & 1][0];
    bf16x8 bfv[4], af[4];
    #pragma unroll
    for (int nf = 0; nf < 4; ++nf)
      bfv[nf] = *(const bf16x8*)(sB + boffb + (nf << 10));
    #pragma unroll
    for (int mf = 0; mf < 4; ++mf)
      af[mf] = *(const bf16x8*)(sA + aoffb + (mf << 10));
    // 4) MFMA cluster
    __builtin_amdgcn_s_setprio(1);
    #pragma unroll
    for (int mf = 0; mf < 4; ++mf)
      #pragma unroll
      for (int nf = 0; nf < 4; ++nf)
        acc[mf][nf] = __builtin_amdgcn_mfma_f32_16x16x32_bf16(bfv[nf], af[mf],
                                                              acc[mf][nf], 0, 0, 0);
    __builtin_amdgcn_s_setprio(0);
    // 5) tanh(kt+1) -> A[(kt+1)&1]  (vm-wait here drains ep + B(kt+1), not B(kt+2))
    if (kt < 15) {
      u16x4 o;
      #pragma unroll
      for (int i = 0; i < 4; ++i) o[i] = f2bf(fast_tanh(e[i] + p[i]));
      *(u16x4*)((kt & 1) ? awr0 : awr1) = o;
      asm volatile("s_waitcnt lgkmcnt(0)" ::: "memory");
      __builtin_amdgcn_s_barrier();
    }
  }

  // ---- epilogue through LDS (r6 pattern), reusing B slots as [16][516] f32
  __syncthreads();
  float (*epi)[516] = (float (*)[516])&Bl[0][0];
  #pragma unroll
  for (int mf = 0; mf < 4; ++mf) {
    if (mf) __syncthreads();
    #pragma unroll
    for (int nf = 0; nf < 4; ++nf) {
      fvec4 o = acc[mf][nf] + bvv[nf];
      *(fvec4*)&epi[fr][colw + (nf << 4)] = o;
    }
    __syncthreads();
    #pragma unroll
    for (int j = 0; j < 4; ++j) {
      const int idx = (wid << 2) + j;
      const int row = idx >> 1, seg = idx & 1;
      fvec4 v = *(const fvec4*)&epi[row][(seg << 8) + (lane << 2)];
      *(fvec4*)&out[(size_t)(m0 + (mf << 4) + row) * 1024 + cb0 +
                    (seg << 8) + (lane << 2)] = v;
    }
  }
}

extern "C" void kernel_launch(void* const* d_in, const int* in_sizes, int n_in,
                              void* d_out, int out_size, void* d_ws, size_t ws_size,
                              hipStream_t stream) {
  const float* enc   = (const float*)d_in[0];
  const float* pred  = (const float*)d_in[1];
  const float* W_enc = (const float*)d_in[2];
  const float* b_enc = (const float*)d_in[3];
  const float* W_dec = (const float*)d_in[4];
  const float* b_dec = (const float*)d_in[5];
  const float* W_out = (const float*)d_in[6];
  const float* b_out = (const float*)d_in[7];
  float* out = (float*)d_out;

  uint8_t* ws = (uint8_t*)d_ws;
  float* encp  = (float*)ws;                           // [1024][512] f32, 2 MiB
  float* predp = (float*)(ws + 2097152);               // [256][512]  f32, 0.5 MiB
  unsigned short* bt2 = (unsigned short*)(ws + 2621440);// K-major W_out^T bf16, 1 MiB

  prep_kernel<<<288, 256, 0, stream>>>(enc, W_enc, b_enc, encp,
                                       pred, W_dec, b_dec, predp,
                                       W_out, bt2);
  fused_gemm<<<2048, 512, 0, stream>>>(encp, predp, bt2, b_out, out);
}

// Round 8
// 125.013 us; speedup vs baseline: 1.5339x; 1.3796x over previous
//
#include <hip/hip_runtime.h>
#include <hip/hip_bf16.h>

typedef __attribute__((ext_vector_type(8))) short bf16x8;
typedef __attribute__((ext_vector_type(4))) float f32x4;
typedef __attribute__((ext_vector_type(4))) float fvec4;
typedef __attribute__((ext_vector_type(8))) unsigned short u16x8;

// B=4, T=256, U=64 -> M = 65536 rows; K(J)=512; N(V)=1024

__device__ __forceinline__ unsigned short f2bf(float f) {
  unsigned int u = __builtin_bit_cast(unsigned int, f);
  u += 0x7FFFu + ((u >> 16) & 1u);   // round-to-nearest-even
  return (unsigned short)(u >> 16);
}

__device__ __forceinline__ float fast_tanh(float x) {
  float cx = fminf(fmaxf(x, -9.0f), 9.0f);
  float e2 = __expf(cx + cx);
  return (e2 - 1.0f) * __builtin_amdgcn_rcpf(e2 + 1.0f);
}

// ---- fused prep: enc-proj (blocks 0..127), pred-proj (128..159), W_out^T (160..287)

__device__ __forceinline__ void proj_body(
    const float* __restrict__ x, const float* __restrict__ W,
    const float* __restrict__ bias, float* __restrict__ out,
    int blk, uint8_t* sh) {
  float (*xt)[9] = (float (*)[9])sh;   // [256][9] f32 = 9216 B
  const int tid = threadIdx.x;
  const int row0 = blk << 3;
  #pragma unroll
  for (int i = 0; i < 8; ++i)
    xt[tid][i] = x[(size_t)(row0 + i) * 256 + tid];
  __syncthreads();
  float acc0[8] = {0.f,0.f,0.f,0.f,0.f,0.f,0.f,0.f};
  float acc1[8] = {0.f,0.f,0.f,0.f,0.f,0.f,0.f,0.f};
  #pragma unroll 4
  for (int k = 0; k < 256; ++k) {
    float w0 = W[(size_t)k * 512 + tid];
    float w1 = W[(size_t)k * 512 + tid + 256];
    #pragma unroll
    for (int r = 0; r < 8; ++r) {
      float xv = xt[k][r];
      acc0[r] = fmaf(xv, w0, acc0[r]);
      acc1[r] = fmaf(xv, w1, acc1[r]);
    }
  }
  float b0 = bias[tid], b1 = bias[tid + 256];
  #pragma unroll
  for (int r = 0; r < 8; ++r) {
    out[(size_t)(row0 + r) * 512 + tid]       = acc0[r] + b0;
    out[(size_t)(row0 + r) * 512 + tid + 256] = acc1[r] + b1;
  }
}

// W_out [512 k][1024 n] f32 -> Bt2 K-MAJOR bf16: index =
//   (n>>9)*262144 + (k>>5)*16384 + (n&511)*32 + (k&31)
// -> a register B-frag load (16 n-rows x 8 k) is ONE contiguous 1 KiB segment.
__device__ __forceinline__ void transpose_body(
    const float* __restrict__ W, unsigned short* __restrict__ Bt2,
    int blk, uint8_t* sh) {
  unsigned short (*tile)[65] = (unsigned short (*)[65])sh;  // [64 k][65 n]
  const int k0 = (blk & 7) << 6;
  const int n0 = (blk >> 3) << 6;
  const int tid = threadIdx.x;
  #pragma unroll
  for (int i = 0; i < 16; ++i) {
    int idx = tid + (i << 8);
    int r = idx >> 6, c = idx & 63;        // r = k-off, c = n-off (coalesced read)
    tile[r][c] = f2bf(W[(size_t)(k0 + r) * 1024 + n0 + c]);
  }
  __syncthreads();
  #pragma unroll
  for (int i = 0; i < 16; ++i) {
    int idx = tid + (i << 8);
    int r = idx >> 6, c = idx & 63;        // r = n-off, c = k-off
    int ng = n0 + r, kg = k0 + c;
    size_t dst = ((size_t)(ng >> 9) << 18) + ((size_t)(kg >> 5) << 14)
               + ((ng & 511) << 5) + (kg & 31);
    Bt2[dst] = tile[c][r];
  }
}

__global__ __launch_bounds__(256) void prep_kernel(
    const float* __restrict__ enc, const float* __restrict__ We,
    const float* __restrict__ be, float* __restrict__ encp,
    const float* __restrict__ pred, const float* __restrict__ Wd,
    const float* __restrict__ bd, float* __restrict__ predp,
    const float* __restrict__ Wo, unsigned short* __restrict__ Bt2) {
  __shared__ uint8_t sh[9216];
  const int b = blockIdx.x;
  if (b < 128)       proj_body(enc, We, be, encp, b, sh);
  else if (b < 160)  proj_body(pred, Wd, bd, predp, b - 128, sh);
  else               transpose_body(Wo, Bt2, b - 160, sh);
}

// ---- fused joint+gemm: BM=64, BN=512, K=512, 8 waves x (64M x 64N).
// CONCURRENCY IS THE POINT (r7 lesson: 1 block/CU + barrier/K-step = serialized
// phases, 40 us naked write-drain):
//  * A = bf16(tanh(encp+predp)) once into 64 KiB XOR-swizzled LDS -> K-loop has
//    ZERO barriers (A read-only; B never touches LDS).
//  * B-frags DIRECT to registers from K-major Bt2: one contiguous 1 KiB segment
//    per load (r5's failure was row-major scatter, not direct-loading itself).
//  * 64 KiB LDS + <=128 regs (launch_bounds(512,4)) -> 2 blocks/CU; their
//    K-loops and epilogue write-drains mutually overlap.
//  * epilogue via LDS re-layout (reuses A buffer) + NONTEMPORAL 1 KiB stores
//    (don't evict Bt2 from L2).
__global__ __launch_bounds__(512, 4) void fused_gemm(
    const float* __restrict__ encp, const float* __restrict__ predp,
    const unsigned short* __restrict__ Bt2, const float* __restrict__ bout,
    float* __restrict__ out) {
  __shared__ uint8_t Alds[65536];   // A: [64 rows][512 bf16] swizzled; epi: [16][516] f32
  const int tid = threadIdx.x;
  const int lane = tid & 63, wid = tid >> 6;
  const int fr = lane & 15, fg = lane >> 4;
  const int b = blockIdx.x;
  const int wg = ((b & 7) << 8) + (b >> 3);   // XCD swizzle, 2048 % 8 == 0 (bijective)
  const int mt = wg >> 1, half = wg & 1;      // half inner: pair shares encp row
  const int m0 = mt << 6;
  const int cb0 = half << 9;

  // per-lane B base in K-major layout: elem = (kt<<14) + (n<<5) + (fg<<3),
  // n = wid*64 + nf*16 + fr.  frag nf offset = nf<<9; kt offset = kt<<14.
  const unsigned short* Bgl =
      Bt2 + ((size_t)half << 18) + (((wid << 6) + fr) << 5) + (fg << 3);

  bf16x8 bA[4], bB[4];
  #pragma unroll
  for (int nf = 0; nf < 4; ++nf)      // issue tile-0 B loads before tanh phase
    bA[nf] = *(const bf16x8*)(Bgl + (nf << 9));

  // ---- phase 0: A tile -> swizzled LDS.  f(row,chunk) = row*1024 + ((chunk^(row&7))<<4)
  {
    const int r = tid >> 3, cb = tid & 7;
    const float* erow = encp + ((size_t)mt << 9);
    const float* prow = predp + ((size_t)(((mt >> 8) << 6) + r) << 9);
    uint8_t* rowbase = Alds + (r << 10);
    #pragma unroll
    for (int c8 = 0; c8 < 8; ++c8) {
      int chunk = cb + (c8 << 3);
      int k8 = chunk << 3;
      fvec4 e0 = *(const fvec4*)(erow + k8);
      fvec4 e1 = *(const fvec4*)(erow + k8 + 4);
      fvec4 p0 = *(const fvec4*)(prow + k8);
      fvec4 p1 = *(const fvec4*)(prow + k8 + 4);
      u16x8 o;
      #pragma unroll
      for (int i = 0; i < 4; ++i) o[i]     = f2bf(fast_tanh(e0[i] + p0[i]));
      #pragma unroll
      for (int i = 0; i < 4; ++i) o[i + 4] = f2bf(fast_tanh(e1[i] + p1[i]));
      *(u16x8*)(rowbase + ((chunk ^ (r & 7)) << 4)) = o;
    }
  }
  __syncthreads();   // A published; K-loop below is barrier-free

  f32x4 acc[4][4];
  f32x4 zero4 = {0.f, 0.f, 0.f, 0.f};
  #pragma unroll
  for (int i = 0; i < 4; ++i)
    #pragma unroll
    for (int j = 0; j < 4; ++j) acc[i][j] = zero4;

  // A read addr: chunk = ((kt<<2)|fg) ^ (fr&7) = ((kt^qh)<<2) | (fg^(fr&3))
  const int qh = (fr >> 2) & 1;
  int arow[4];
  #pragma unroll
  for (int mf = 0; mf < 4; ++mf)
    arow[mf] = ((((mf << 4) + fr)) << 10) + ((fg ^ (fr & 3)) << 4);

  // one K-step: prefetch B(kt+1) into nxt (contiguous 1KiB/instr), read A frags
  // from LDS, 16 MFMA on cur.  No barriers, no LDS writes.
  auto step = [&](int kt, bf16x8 (&cur)[4], bf16x8 (&nxt)[4]) {
    const int ktn = kt < 15 ? kt + 1 : 15;   // last iter: harmless dup reload
    #pragma unroll
    for (int nf = 0; nf < 4; ++nf)
      nxt[nf] = *(const bf16x8*)(Bgl + (ktn << 14) + (nf << 9));
    const int ko = (kt ^ qh) << 6;
    bf16x8 af[4];
    #pragma unroll
    for (int mf = 0; mf < 4; ++mf)
      af[mf] = *(const bf16x8*)(Alds + arow[mf] + ko);
    #pragma unroll
    for (int mf = 0; mf < 4; ++mf)
      #pragma unroll
      for (int nf = 0; nf < 4; ++nf)
        acc[mf][nf] = __builtin_amdgcn_mfma_f32_16x16x32_bf16(cur[nf], af[mf],
                                                              acc[mf][nf], 0, 0, 0);
  };

  #pragma unroll
  for (int kt = 0; kt < 16; kt += 2) {   // static ping-pong (rule #20)
    step(kt,     bA, bB);
    step(kt + 1, bB, bA);
  }

  // ---- epilogue through LDS re-layout (reuse A buffer; A dead now).
  float (*epi)[516] = (float (*)[516])Alds;
  const int colw = (wid << 6) + (fg << 2);
  fvec4 bvv[4];
  #pragma unroll
  for (int nf = 0; nf < 4; ++nf)
    bvv[nf] = *(const fvec4*)&bout[cb0 + colw + (nf << 4)];

  #pragma unroll
  for (int mf = 0; mf < 4; ++mf) {
    __syncthreads();   // K-loop A reads / prev round drain done
    #pragma unroll
    for (int nf = 0; nf < 4; ++nf) {
      fvec4 o = acc[mf][nf] + bvv[nf];
      *(fvec4*)&epi[fr][colw + (nf << 4)] = o;
    }
    __syncthreads();
    #pragma unroll
    for (int j = 0; j < 4; ++j) {
      const int idx = (wid << 2) + j;
      const int row = idx >> 1, seg = idx & 1;
      fvec4 v = *(const fvec4*)&epi[row][(seg << 8) + (lane << 2)];
      __builtin_nontemporal_store(
          v, (fvec4*)&out[(size_t)(m0 + (mf << 4) + row) * 1024 + cb0 +
                          (seg << 8) + (lane << 2)]);
    }
  }
}

extern "C" void kernel_launch(void* const* d_in, const int* in_sizes, int n_in,
                              void* d_out, int out_size, void* d_ws, size_t ws_size,
                              hipStream_t stream) {
  const float* enc   = (const float*)d_in[0];
  const float* pred  = (const float*)d_in[1];
  const float* W_enc = (const float*)d_in[2];
  const float* b_enc = (const float*)d_in[3];
  const float* W_dec = (const float*)d_in[4];
  const float* b_dec = (const float*)d_in[5];
  const float* W_out = (const float*)d_in[6];
  const float* b_out = (const float*)d_in[7];
  float* out = (float*)d_out;

  uint8_t* ws = (uint8_t*)d_ws;
  float* encp  = (float*)ws;                           // [1024][512] f32, 2 MiB
  float* predp = (float*)(ws + 2097152);               // [256][512]  f32, 0.5 MiB
  unsigned short* bt2 = (unsigned short*)(ws + 2621440);// K-major W_out^T bf16, 1 MiB

  prep_kernel<<<288, 256, 0, stream>>>(enc, W_enc, b_enc, encp,
                                       pred, W_dec, b_dec, predp,
                                       W_out, bt2);
  fused_gemm<<<2048, 512, 0, stream>>>(encp, predp, bt2, b_out, out);
}